// Round 11
// baseline (121.093 us; speedup 1.0000x reference)
//
#include <hip/hip_runtime.h>
#include <cstdint>
#include <cstddef>

// Problem constants (match reference)
#define BB    64
#define TB    2000
#define KB    256
#define WPB   125      // lse wave-jobs per batch
#define RPW   16       // rows per lse wave-job (125*16 = 2000)
#define NLSEB 2000     // lse blocks (4 waves each): 64*125/4

constexpr float LOG2E = 1.4426950408889634f;
constexpr float LN2f  = 0.6931471805599453f;
constexpr float WBF   = 0.36787944117144233f;   // exp(-1)

__device__ __forceinline__ float exp2i(int k) {  // exact 2^k, k in [-126,127]
  return __uint_as_float((uint32_t)(127 + k) << 23);
}
// lane i <- lane i-1 (lane 0 <- 0): DPP wave_shr:1, pure VALU (validated r4-r10)
__device__ __forceinline__ float shr1z(float v) {
  return __int_as_float(__builtin_amdgcn_update_dpp(
      0, __float_as_int(v), 0x138, 0xF, 0xF, true));
}
// wave64 max, pure-VALU DPP tree (validated r6-r10); uniform via readlane(63)
__device__ __forceinline__ float dmax64(float v) {
#define DSTEP(ctrl, rm, bc)                                                  \
  { float t = __int_as_float(__builtin_amdgcn_update_dpp(                    \
        __float_as_int(v), __float_as_int(v), (ctrl), (rm), 0xF, (bc)));     \
    v = fmaxf(v, t); }
  DSTEP(0x111, 0xF, true) DSTEP(0x112, 0xF, true) DSTEP(0x114, 0xF, true)
  DSTEP(0x118, 0xF, true) DSTEP(0x142, 0xA, false) DSTEP(0x143, 0xC, false)
#undef DSTEP
  return __int_as_float(__builtin_amdgcn_readlane(__float_as_int(v), 63));
}
// wave64 sum, pure-VALU DPP tree; total valid in lane 63 (validated r6-r10)
__device__ __forceinline__ float dsum64(float v) {
#define DSTEP(ctrl, rm, bc)                                                  \
  { float t = __int_as_float(__builtin_amdgcn_update_dpp(                    \
        __float_as_int(v), __float_as_int(v), (ctrl), (rm), 0xF, (bc)));     \
    v += t; }
  DSTEP(0x111, 0xF, true) DSTEP(0x112, 0xF, true) DSTEP(0x114, 0xF, true)
  DSTEP(0x118, 0xF, true) DSTEP(0x142, 0xA, false) DSTEP(0x143, 0xC, false)
#undef DSTEP
  return v;
}
__device__ __forceinline__ float wsum64(float v) {
#pragma unroll
  for (int m = 32; m >= 1; m >>= 1) v += __shfl_xor(v, m, 64);
  return v;
}

typedef const __attribute__((address_space(1))) unsigned int* gas1p;
typedef __attribute__((address_space(3))) unsigned int* las3p;

// ---------------------------------------------------------------------------
// blocks [0,64): per-batch scan. Wave 0 = consumer (513 states, 4 pairs/lane,
// 1 DPP shift/step, zero transcendentals, zero barriers). Waves 1-3 =
// producers: load x rows, 4 exp2/row (bias bakes key-mask + e^1-fold),
// ds_write weight rows into an 8-group LDS ring. NOTHING else (r11: lse
// removed from producers — its dsum64/log latency chains rate-locked the
// whole block at ~140 cyc/step in r8-r10).
// blocks >= 64: row log-sum-exp, 16 rows/wave, DPP sum (r5/r6-proven).
// 86KB LDS pad -> scan blocks own their CU exclusively.
// Flag protocol proven r7-r10: per-wave in-order DS retirement orders
// data-write -> flag-write and data-read -> consG-write.
// ---------------------------------------------------------------------------
__global__ __launch_bounds__(256, 1)
void fsl_main(const float* __restrict__ x, const int* __restrict__ key_lens,
              const int* __restrict__ query_lens, float* __restrict__ partial,
              float* __restrict__ alast, float* __restrict__ aprev) {
  __shared__ __align__(16) char ring[86016];   // 64KB ring (8 x 8KB) + pad
  __shared__ __align__(16) int prodG[4];       // 3 flags + pad (one b128 read)
  __shared__ int consG;

  const int tid  = threadIdx.x;
  const int lane = tid & 63;
  const int w    = tid >> 6;

  if (blockIdx.x < BB) {
    const int b    = blockIdx.x;
    const int kl   = key_lens[b];
    const int qlen = query_lens[b];
    const int total = qlen - 1;                // live steps t = 1..total
    const int ng    = (total + 7) >> 3;        // 8-step groups (>=125)
    const float* xb  = x + (size_t)b * (TB * KB);
    const char*  xbc = (const char*)xb;
    const int lane16 = lane << 4;

    if (tid == 0) { prodG[0] = 0; prodG[1] = 0; prodG[2] = 0; prodG[3] = 0x7fffffff; consG = 0; }
    __syncthreads();                           // the ONLY barrier

    if (w == 0) {
      // =================== consumer: the scan wave ===================
      float a0 = 0.f, a1 = 0.f, a2 = 0.f, a3 = 0.f;
      float b0 = 0.f, b1 = 0.f, b2 = 0.f, b3 = 0.f, s512 = 0.f;
      if (lane == 0) { a0 = WBF; b0 = __builtin_amdgcn_exp2f(xb[0] * LOG2E); }
      int Cw = 0;
      float m_red = dmax64(fmaxf(a0, b0));

      float4 e0, e1, e2, e3, e4, e5, e6, e7;
      float4 f0, f1, f2, f3, f4, f5, f6, f7;
      float4 g0, g1, g2, g3, g4, g5, g6, g7;

      // one ds_read_b128 of all 3 flags; pure spin (scan CU is exclusive)
#define POLL(GN) do {                                                        \
    const int tgt_ = (GN);                                                   \
    for (;;) {                                                               \
      __asm__ __volatile__("" ::: "memory");                                 \
      const int4 fl_ = *(const int4*)prodG;                                  \
      if (min(fl_.x, min(fl_.y, fl_.z)) >= tgt_) break;                      \
    }                                                                        \
    __asm__ __volatile__("" ::: "memory");                                   \
  } while (0)

#define LD8(E, g) do {                                                       \
    const char* sb_ = ring + (((g) & 7) << 13) + lane16;                     \
    E##0 = *(const float4*)(sb_);                                            \
    E##1 = *(const float4*)(sb_ + 1024);                                     \
    E##2 = *(const float4*)(sb_ + 2048);                                     \
    E##3 = *(const float4*)(sb_ + 3072);                                     \
    E##4 = *(const float4*)(sb_ + 4096);                                     \
    E##5 = *(const float4*)(sb_ + 5120);                                     \
    E##6 = *(const float4*)(sb_ + 6144);                                     \
    E##7 = *(const float4*)(sb_ + 7168);                                     \
  } while (0)

      // EV holds the PRECOMPUTED weights for this step (4 odd-state weights)
#define STEP1(EV) do {                                                       \
    const float pm1 = shr1z(b3);                                             \
    const float t0_ = a0 + pm1;                                              \
    const float t1_ = a1 + b0;                                               \
    const float t2_ = a2 + b1;                                               \
    const float t3_ = a3 + b2;                                               \
    s512 = s512 + b3;                                                        \
    b0 = (b0 + t0_) * EV.x;                                                  \
    b1 = (b1 + t1_) * EV.y;                                                  \
    b2 = (b2 + t2_) * EV.z;                                                  \
    b3 = (b3 + t3_) * EV.w;                                                  \
    a0 = t0_; a1 = t1_; a2 = t2_; a3 = t3_;                                  \
  } while (0)

#define STEP1G(EV, J) do { if ((J) < rem_) { STEP1(EV); } } while (0)

#define RUN8(E)  do { STEP1(E##0); STEP1(E##1); STEP1(E##2); STEP1(E##3);    \
                      STEP1(E##4); STEP1(E##5); STEP1(E##6); STEP1(E##7); } while (0)
#define RUN8G(E, RM) do { const int rem_ = (RM);                             \
                      STEP1G(E##0,0); STEP1G(E##1,1); STEP1G(E##2,2);        \
                      STEP1G(E##3,3); STEP1G(E##4,4); STEP1G(E##5,5);        \
                      STEP1G(E##6,6); STEP1G(E##7,7); } while (0)

#define APPLY() do {                                                         \
    int e_ = (int)((__float_as_uint(m_red) >> 23) & 0xFF) - 127;             \
    if (!(m_red > 0.f)) e_ = -24;                                            \
    const int k_ = e_ + 24;              /* normalize max to 2^-24 */        \
    if (k_ > 126) {                                                          \
      const int kh_ = k_ >> 1;                                               \
      const float s1_ = exp2i(-kh_), s2_ = exp2i(-(k_ - kh_));               \
      a0 *= s1_; a1 *= s1_; a2 *= s1_; a3 *= s1_;                            \
      b0 *= s1_; b1 *= s1_; b2 *= s1_; b3 *= s1_; s512 *= s1_;               \
      a0 *= s2_; a1 *= s2_; a2 *= s2_; a3 *= s2_;                            \
      b0 *= s2_; b1 *= s2_; b2 *= s2_; b3 *= s2_; s512 *= s2_;               \
    } else {                                                                 \
      const float s_ = exp2i(-k_);                                           \
      a0 *= s_; a1 *= s_; a2 *= s_; a3 *= s_;                                \
      b0 *= s_; b1 *= s_; b2 *= s_; b3 *= s_; s512 *= s_;                    \
    }                                                                        \
    Cw += k_;                                                                \
  } while (0)

#define MEASURE() do {                                                       \
    float ml_ = fmaxf(fmaxf(fmaxf(a0, a1), fmaxf(a2, a3)),                   \
                      fmaxf(fmaxf(b0, b1), fmaxf(b2, b3)));                  \
    ml_ = fmaxf(ml_, s512);                                                  \
    m_red = dmax64(ml_);                                                     \
  } while (0)

#define RUNGRP(E, G) do {                                                    \
    if (8 * (G) + 8 <= total) { RUN8(E); }                                   \
    else { RUN8G(E, total - 8 * (G)); }                                      \
    APPLY(); MEASURE();                                                      \
  } while (0)

      POLL(3);
      LD8(e, 0);
      if (1 < ng) LD8(f, 1);
      if (2 < ng) LD8(g, 2);
      int cg = 0;
      // -------- main loop: fully-live groups, prefetch always valid --------
      while (cg + 6 <= ng && 8 * (cg + 3) <= total) {
        POLL(cg + 6);
        RUN8(e); APPLY(); MEASURE(); LD8(e, cg + 3);
        RUN8(f); APPLY(); MEASURE(); LD8(f, cg + 4);
        RUN8(g); APPLY(); MEASURE(); LD8(g, cg + 5);
        __asm__ __volatile__("" ::: "memory");
        if (lane == 0) *(volatile int*)&consG = cg + 6;  // after LD8s (in-order DS)
        cg += 3;
      }
      // -------- guarded tail --------
      for (; cg < ng; cg += 3) {
        POLL(min(cg + 6, ng));
        RUNGRP(e, cg);
        if (cg + 3 < ng) LD8(e, cg + 3);
        if (cg + 1 < ng) {
          RUNGRP(f, cg + 1);
          if (cg + 4 < ng) LD8(f, cg + 4);
        }
        if (cg + 2 < ng) {
          RUNGRP(g, cg + 2);
          if (cg + 5 < ng) LD8(g, cg + 5);
        }
        __asm__ __volatile__("" ::: "memory");
        if (lane == 0) *(volatile int*)&consG = cg + 6;
      }
#undef POLL
#undef LD8
#undef STEP1
#undef STEP1G
#undef RUN8
#undef RUN8G
#undef APPLY
#undef MEASURE
#undef RUNGRP

      // readout: a_last = state 2*kl, a_prev = state 2*kl-1
      float* ev = (float*)ring;
      float* od = (float*)(ring + 4096);
      *(float4*)(ev + (lane << 2)) = make_float4(a0, a1, a2, a3);
      *(float4*)(od + (lane << 2)) = make_float4(b0, b1, b2, b3);
      if (lane == 63) *(float*)(ring + 8192) = s512;
      __asm__ __volatile__("" ::: "memory");
      if (lane == 0) {
        const float aL = (kl < 256) ? ev[kl] : *(float*)(ring + 8192);
        const float aP = od[kl - 1];
        const float dC = (float)Cw - (float)total * LOG2E;  // e-fold removal
        alast[b] = (log2f(aL) + dC) * LN2f;
        aprev[b] = (log2f(aP) + dC) * LN2f;
      }
    } else {
      // ========== producers: waves 1..3 — exp2 + ds_write ONLY ==========
      const int pw = w - 1;                    // handles groups g % 3 == pw
      const int c0 = lane << 2;
      const float bs0 = (c0 + 0 < kl) ? LOG2E : -20000.f;
      const float bs1 = (c0 + 1 < kl) ? LOG2E : -20000.f;
      const float bs2 = (c0 + 2 < kl) ? LOG2E : -20000.f;
      const float bs3 = (c0 + 3 < kl) ? LOG2E : -20000.f;
      volatile int* vc = &consG;

      float4 A0, A1, A2, A3, A4, A5, A6, A7;
      float4 B0, B1, B2, B3, B4, B5, B6, B7;
      float4 C0, C1, C2, C3, C4, C5, C6, C7;

#define LOADG(P, GG) do {                                                    \
    const int rb_ = 8 * (GG) + 1;                                            \
    P##0 = *(const float4*)(xbc + (size_t)min(rb_ + 0, TB - 1) * 1024 + lane16); \
    P##1 = *(const float4*)(xbc + (size_t)min(rb_ + 1, TB - 1) * 1024 + lane16); \
    P##2 = *(const float4*)(xbc + (size_t)min(rb_ + 2, TB - 1) * 1024 + lane16); \
    P##3 = *(const float4*)(xbc + (size_t)min(rb_ + 3, TB - 1) * 1024 + lane16); \
    P##4 = *(const float4*)(xbc + (size_t)min(rb_ + 4, TB - 1) * 1024 + lane16); \
    P##5 = *(const float4*)(xbc + (size_t)min(rb_ + 5, TB - 1) * 1024 + lane16); \
    P##6 = *(const float4*)(xbc + (size_t)min(rb_ + 6, TB - 1) * 1024 + lane16); \
    P##7 = *(const float4*)(xbc + (size_t)min(rb_ + 7, TB - 1) * 1024 + lane16); \
  } while (0)

#define PR1(V, J) do {                                                       \
    float4 wv_;                                                              \
    wv_.x = __builtin_amdgcn_exp2f(fmaf(V.x, LOG2E, bs0));                   \
    wv_.y = __builtin_amdgcn_exp2f(fmaf(V.y, LOG2E, bs1));                   \
    wv_.z = __builtin_amdgcn_exp2f(fmaf(V.z, LOG2E, bs2));                   \
    wv_.w = __builtin_amdgcn_exp2f(fmaf(V.w, LOG2E, bs3));                   \
    *(float4*)(dstb_ + ((J) << 10)) = wv_;                                   \
  } while (0)

#define PROC(P, GG) do {                                                     \
    if ((GG) >= 8) {                        /* ring slot reuse */            \
      int c_ = *vc;                                                          \
      while (c_ < (GG) - 7) { __builtin_amdgcn_s_sleep(2); c_ = *vc; }       \
      __asm__ __volatile__("" ::: "memory");                                 \
    }                                                                        \
    char* dstb_ = ring + (((GG) & 7) << 13) + lane16;                        \
    PR1(P##0, 0); PR1(P##1, 1); PR1(P##2, 2); PR1(P##3, 3);                  \
    PR1(P##4, 4); PR1(P##5, 5); PR1(P##6, 6); PR1(P##7, 7);                  \
    __asm__ __volatile__("s_waitcnt lgkmcnt(0)" ::: "memory");               \
    if (lane == 0) *(volatile int*)&prodG[pw] = (GG) + 3;                    \
  } while (0)

      LOADG(A, pw); LOADG(B, pw + 3);
      int g = pw;
      for (;;) {
        LOADG(C, g + 6);
        PROC(A, g);
        g += 3; if (g >= ng) break;
        LOADG(A, g + 6);
        PROC(B, g);
        g += 3; if (g >= ng) break;
        LOADG(B, g + 6);
        PROC(C, g);
        g += 3; if (g >= ng) break;
      }
#undef LOADG
#undef PR1
#undef PROC
      __asm__ __volatile__("" ::: "memory");
      if (lane == 0) *(volatile int*)&prodG[pw] = 0x7fffffff;
    }

  } else {
    // -------- lse row partials: 16 rows/wave, DPP sum, no max pass --------
    // (r5/r6-proven; runs on the 192 CUs the scan doesn't occupy)
    const int gwid = (blockIdx.x - BB) * 4 + w;            // [0, 8000)
    const int b    = gwid / WPB;
    const int widx = gwid - b * WPB;
    const int kl   = key_lens[b];
    const int qlen = query_lens[b];
    const float* xb = x + (size_t)b * (TB * KB);
    const int c0 = lane * 4;
    const float bA = (c0 + 0 < kl) ? 0.f : -20000.f;
    const float bBv= (c0 + 1 < kl) ? 0.f : -20000.f;
    const float bC = (c0 + 2 < kl) ? 0.f : -20000.f;
    const float bD = (c0 + 3 < kl) ? 0.f : -20000.f;
    float acc = 0.f;
    const int tbase = widx * RPW;
#pragma unroll 4
    for (int k = 0; k < RPW; ++k) {
      const int t = tbase + k;
      const float4 v = *(const float4*)(xb + (size_t)t * KB + c0);
      float s = __builtin_amdgcn_exp2f(fmaf(v.x, LOG2E, bA))
              + __builtin_amdgcn_exp2f(fmaf(v.y, LOG2E, bBv))
              + __builtin_amdgcn_exp2f(fmaf(v.z, LOG2E, bC))
              + __builtin_amdgcn_exp2f(fmaf(v.w, LOG2E, bD));
      s = dsum64(s);                           // total in lane 63
      s += WBF;                                // blank term exp(-1)
      const float l2 = __builtin_amdgcn_logf(s);   // log2(s)
      acc += (t < qlen) ? l2 : 0.f;
    }
    if (lane == 63) partial[gwid] = acc * LN2f;
  }
}

// ---------------------------------------------------------------------------
// finish: per-batch SumLse + loss + mean, one block (r5-proven).
// ---------------------------------------------------------------------------
__global__ __launch_bounds__(256)
void fsl_finish(const float* __restrict__ partial, const int* __restrict__ key_lens,
                const float* __restrict__ alast, const float* __restrict__ aprev,
                float* __restrict__ out) {
  const int tid = threadIdx.x;
  const int b = tid >> 2, q = tid & 3;
  float s = 0.f;
  for (int j = q; j < WPB; j += 4) s += partial[b * WPB + j];
  s += __shfl_xor(s, 1, 64);
  s += __shfl_xor(s, 2, 64);
  float lossb = 0.f;
  if (q == 0) {
    const float SumLse = s;
    const float al = alast[b], ap = aprev[b];
    const float mx = fmaxf(al, ap);
    const float lae = (mx == -INFINITY) ? -INFINITY
                                        : mx + log1pf(expf(-fabsf(al - ap)));
    const float nll = SumLse - lae;
    const int kl = key_lens[b];
    float lv = nll / (float)max(kl, 1);
    if (nll > 5e29f) lv = 0.f;
    lossb = lv;
  }
  float v = wsum64(lossb);
  __shared__ float sm[4];
  if ((tid & 63) == 0) sm[tid >> 6] = v;
  __syncthreads();
  if (tid == 0) out[0] = ((sm[0] + sm[1]) + (sm[2] + sm[3])) * (1.0f / 64.0f);
}

extern "C" void kernel_launch(void* const* d_in, const int* in_sizes, int n_in,
                              void* d_out, int out_size, void* d_ws, size_t ws_size,
                              hipStream_t stream) {
  const float* x     = (const float*)d_in[0];
  const int*   klens = (const int*)d_in[1];
  const int*   qlens = (const int*)d_in[2];
  float* out = (float*)d_out;

  float* partial = (float*)d_ws;            // 64*125 = 8000 floats
  float* alast   = partial + BB * WPB;      // 64
  float* aprev   = alast + BB;              // 64

  fsl_main  <<<BB + NLSEB, 256, 0, stream>>>(x, klens, qlens, partial, alast, aprev);
  fsl_finish<<<1, 256, 0, stream>>>(partial, klens, alast, aprev, out);
}